// Round 1
// baseline (243.076 us; speedup 1.0000x reference)
//
#include <hip/hip_runtime.h>

// TreeCRF inside pass, 32 channels, perfect binary tree in heap layout.
// contrib[i] = LSE_j(trans[i,j] + child[j]) = m + log(sum_j E[i,j]*exp(child[j]-m)),
// E = exp(trans) precomputed (transposed) in LDS, m = max_j child[j].

__global__ __launch_bounds__(256) void treecrf_level(
    const float* __restrict__ child,   // [2W][32] child rows
    const float* __restrict__ em,      // emissions base [n_nodes][32]
    const float* __restrict__ trans,   // [32][32]
    float* __restrict__ out,           // [W][32]
    int W)
{
    __shared__ float ET[1024];         // ET[j*32+i] = exp(trans[i*32+j])
    int t = threadIdx.x;
#pragma unroll
    for (int r = 0; r < 4; ++r) {
        int idx = t + r * 256;
        int j = idx >> 5, i = idx & 31;
        ET[idx] = __expf(trans[i * 32 + j]);
    }
    __syncthreads();

    int q = blockIdx.x * 256 + t;      // child index in [0, 2W); grid is exact
    const float4* xr = (const float4*)(child + (size_t)q * 32);
    float x[32];
#pragma unroll
    for (int k = 0; k < 8; ++k) {
        float4 v = xr[k];
        x[4 * k + 0] = v.x; x[4 * k + 1] = v.y;
        x[4 * k + 2] = v.z; x[4 * k + 3] = v.w;
    }
    float m = x[0];
#pragma unroll
    for (int j = 1; j < 32; ++j) m = fmaxf(m, x[j]);
#pragma unroll
    for (int j = 0; j < 32; ++j) x[j] = __expf(x[j] - m);   // c[j] in (0,1]

    float y[32];
#pragma unroll
    for (int i = 0; i < 32; ++i) y[i] = 0.0f;
#pragma unroll
    for (int j = 0; j < 32; ++j) {
        float cv = x[j];
        const float4* er = (const float4*)(ET + j * 32);
#pragma unroll
        for (int k = 0; k < 8; ++k) {
            float4 e = er[k];                 // wave-uniform ds_read_b128 broadcast
            y[4 * k + 0] = fmaf(e.x, cv, y[4 * k + 0]);
            y[4 * k + 1] = fmaf(e.y, cv, y[4 * k + 1]);
            y[4 * k + 2] = fmaf(e.z, cv, y[4 * k + 2]);
            y[4 * k + 3] = fmaf(e.w, cv, y[4 * k + 3]);
        }
    }
    // contrib[i] = m + log(y[i]); sum with partner lane (sibling child q^1).
#pragma unroll
    for (int i = 0; i < 32; ++i) {
        float cb = m + __logf(y[i]);
        x[i] = cb + __shfl_xor(cb, 1);        // both lanes get left+right sum
    }
    // lane pair (2p, 2p+1) writes the two contiguous 64B halves of parent row p
    int p = q >> 1, h = q & 1;
    const float4* emr = (const float4*)(em + (size_t)(W - 1 + p) * 32 + h * 16);
    float4* outr = (float4*)(out + (size_t)p * 32 + h * 16);
#pragma unroll
    for (int k = 0; k < 4; ++k) {
        float4 e = emr[k];
        float4 o;
        o.x = e.x + x[h * 16 + 4 * k + 0];
        o.y = e.y + x[h * 16 + 4 * k + 1];
        o.z = e.z + x[h * 16 + 4 * k + 2];
        o.w = e.w + x[h * 16 + 4 * k + 3];
        outr[k] = o;
    }
}

// Fused tail: widths W0..1 in one block (256 threads), children staged in LDS.
__global__ __launch_bounds__(256) void treecrf_tail(
    const float* __restrict__ child0,  // [2*W0][32] (global, from last level kernel)
    const float* __restrict__ em,
    const float* __restrict__ trans,
    float* __restrict__ out_root,      // [32]
    int W0)
{
    __shared__ float ET[1024];
    __shared__ float C[128 * 33];      // exp(child-m) rows, stride 33
    __shared__ float M[128];
    __shared__ float S0[64 * 33];      // parent score ping-pong
    __shared__ float S1[32 * 33];
    int t = threadIdx.x;
    for (int idx = t; idx < 1024; idx += 256) {
        int j = idx >> 5, i = idx & 31;
        ET[idx] = __expf(trans[i * 32 + j]);
    }
    __syncthreads();

    int Wl = W0;
    int lvl = 0;
    while (Wl >= 1) {
        int nc = 2 * Wl;
        // phase 1: per-child max + exp rows into C
        for (int q = t; q < nc; q += 256) {
            float x[32];
            if (lvl == 0) {
#pragma unroll
                for (int j = 0; j < 32; ++j) x[j] = child0[q * 32 + j];
            } else {
                const float* src = (lvl & 1) ? S0 : S1;
#pragma unroll
                for (int j = 0; j < 32; ++j) x[j] = src[q * 33 + j];
            }
            float m = x[0];
#pragma unroll
            for (int j = 1; j < 32; ++j) m = fmaxf(m, x[j]);
            M[q] = m;
#pragma unroll
            for (int j = 0; j < 32; ++j) C[q * 33 + j] = __expf(x[j] - m);
        }
        __syncthreads();
        // phase 2: one thread per (parent, channel)
        float* dst = (lvl & 1) ? S0 : S1;   // lvl0 -> S0? no: lvl0 writes S0
        dst = (lvl & 1) ? S1 : S0;
        int total = 32 * Wl;
        for (int idx = t; idx < total; idx += 256) {
            int p = idx >> 5, i = idx & 31;
            const float* cl = C + (2 * p) * 33;
            const float* cr = C + (2 * p + 1) * 33;
            float yl = 0.0f, yr = 0.0f;
#pragma unroll
            for (int j = 0; j < 32; ++j) {
                float e = ET[j * 32 + i];
                yl = fmaf(e, cl[j], yl);
                yr = fmaf(e, cr[j], yr);
            }
            float sc = em[(size_t)(Wl - 1 + p) * 32 + i]
                     + M[2 * p] + __logf(yl)
                     + M[2 * p + 1] + __logf(yr);
            if (Wl == 1) out_root[i] = sc;
            else dst[p * 33 + i] = sc;
        }
        __syncthreads();
        Wl >>= 1;
        ++lvl;
    }
}

extern "C" void kernel_launch(void* const* d_in, const int* in_sizes, int n_in,
                              void* d_out, int out_size, void* d_ws, size_t ws_size,
                              hipStream_t stream)
{
    const float* em = (const float*)d_in[0];
    const float* trans = (const float*)d_in[1];
    int n_nodes = in_sizes[0] / 32;          // 262143
    int n_leaves = (n_nodes + 1) / 2;        // 131072

    // ping-pong score buffers in workspace (needs ~12 MB)
    float* bufA = (float*)d_ws;
    float* bufB = bufA + (size_t)(n_leaves / 2) * 32;

    const float* child = em + (size_t)(n_leaves - 1) * 32;  // leaves
    int W = n_leaves / 2;                    // 65536
    bool toA = true;
    while (W >= 128) {
        float* o = toA ? bufA : bufB;
        treecrf_level<<<dim3((2 * W) / 256), dim3(256), 0, stream>>>(
            child, em, trans, o, W);
        child = o;
        toA = !toA;
        W >>= 1;
    }
    // W == 64 here; fused tail does widths 64..1
    treecrf_tail<<<dim3(1), dim3(256), 0, stream>>>(
        child, em, trans, (float*)d_out, W);
}